// Round 5
// baseline (693.195 us; speedup 1.0000x reference)
//
#include <hip/hip_runtime.h>
#include <stdint.h>

// ---------------- problem constants ----------------
#define NSTEP 100
#define FEAT  1024
#define SPIN_CAP (1 << 16)   // bounded waits

typedef __attribute__((ext_vector_type(8)))  short short8;
typedef __attribute__((ext_vector_type(4)))  float fx4;
typedef __attribute__((ext_vector_type(16))) float fx16;
typedef __attribute__((ext_vector_type(2)))  unsigned int u32x2;
typedef __attribute__((ext_vector_type(4)))  int i32x4;

// ---------------- workspace layout (bytes) ----------------
// R17 = R16 (free-running poll, 607us) + 4-WAY ACCUMULATOR SPLIT. Theory:
// the 16 MFMAs ran as ONE serial dependency chain through a single acc
// (acc = mfma(A[i],b,acc)), entirely after the vmcnt(0) drain -> 16 x L_dep
// (L_dep ~32-64cy for dependent 32x32x16) = 0.25-0.45us on the critical
// path, twice per step. Fix: 4 independent chains (i mod 4), merged by 3
// vector adds; chain -> 4 x L_dep + ~100cy. VGPRs +48 are free (grid=256
// blocks on 256 CUs -> 1 block/CU; occupancy can't drop).
// Hardware facts R4-R16: DATA plane is XCD-L2-local (sc0, R5); flag
// SIGNALING must be agent-scope at the LLC (~1-1.5us/hop) -- L2-scope flag
// polling falsified 3x (R4 atomics, R6 stores, R11 probe); poll-RATE-
// reduction falsified (R10); flag-per-128B-line: -45us (R13); store-flags
// (no RMW): -20us (R14); blocking-poll pipelining via vmcnt(N): falsified,
// conflates with fused A-loads (R15, +150us); free-running monotone poll
// (no waitcnt in loop): -34us (R16); single-wave and per-wave-tile
// structures regressed (R8/R9): 4-SIMD split-K + 2 barriers is the local opt.
// Exchange: parity dbuf, 8 groups x (32 rows x 1024 cols) bf16; per-wave
// value-encoded flags (line = 4 wave-words; init=1, ca1@t=t+1, ec3@t=t+2).
// Element (group-local row m, col c) at short index ((c>>3)*32+m)*8+(c&7).
#define OFF_EC3   0u
#define OFF_CA1   (1u << 20)
#define OFF_DRIVE (2u << 20)
#define OFF_EC3F  (OFF_DRIVE + 425984u)   // drive needs 100*1024*4 = 409600
#define OFF_CA1F  (OFF_EC3F + 32768u)     // 256 lines * 128B (4 wave-words each)
#define OFF_DRVF  (OFF_CA1F + 32768u)     // 256 lines * 128B
#define OFF_GRP   (OFF_DRVF + 4096u)      // 32 lines * 128B
#define WS_NEED   (OFF_GRP + 4096u)       // grpmask lines @+0, grpcnt lines @+2048

#define FSTR 32                        // ints per flag line (128 B)

#define GSTRIDE 32768                  // shorts per group (32*1024)
#define PSTRIDE (8 * GSTRIDE)          // shorts per parity buffer

// ---------------- output layout (float elems) ----------------
#define O_ACT 0
#define O_E3H 512
#define O_E5H (512 + 102400)
#define O_CAH (512 + 204800)
#define O_E3  (512 + 307200)
#define O_E5  (O_E3 + 262144)
#define O_CA  (O_E5 + 262144)

// ---------------- LDS layout (bytes) ----------------
#define LDS_W1    0
#define LDS_W2    65536
#define LDS_RED4  131072               // 4*1024 f32 = 16384
#define LDS_DRV   147456               // 100*32 f32 = 12800
#define LDS_UNI   160256               // 1 int
#define LDS_TOTAL 160272               // <= 163840

__device__ __forceinline__ unsigned short f2bf(float x) {
  uint32_t u = __builtin_bit_cast(uint32_t, x);
  uint32_t r = (u + 0x7FFFu + ((u >> 16) & 1u)) >> 16;   // RNE
  return (unsigned short)r;
}
__device__ __forceinline__ float sigm(float x) { return 1.0f / (1.0f + __expf(-x)); }

#define VM_DRAIN() asm volatile("s_waitcnt vmcnt(0)" ::: "memory")

// data-plane store: uni -> dirty line in shared XCD L2; else -> LLC coherent
__device__ __forceinline__ void ex_store(void* p, u32x2 v, bool uni) {
  if (uni) asm volatile("global_store_dwordx2 %0, %1, off sc0"     :: "v"(p), "v"(v) : "memory");
  else     asm volatile("global_store_dwordx2 %0, %1, off sc0 sc1" :: "v"(p), "v"(v) : "memory");
}
__device__ __forceinline__ void llc_store_f32(float* p, float v) {
  asm volatile("global_store_dword %0, %1, off sc0 sc1" :: "v"(p), "v"(v) : "memory");
}
// control plane: agent scope at the LLC, always (the only HW-working protocol)
// Value-encoded flags: plain agent-scope store (no RMW), monotone values.
__device__ __forceinline__ void flag_store(int* p, int v) {
  __hip_atomic_store(p, v, __ATOMIC_RELAXED, __HIP_MEMORY_SCOPE_AGENT);
}
__device__ __forceinline__ void flag_add(int* p) {            // off-critical-path only
  __hip_atomic_fetch_add(p, 1, __ATOMIC_RELAXED, __HIP_MEMORY_SCOPE_AGENT);
}
__device__ __forceinline__ int flag_peek(const int* p) {
  return __hip_atomic_load(p, __ATOMIC_RELAXED, __HIP_MEMORY_SCOPE_AGENT);
}
__device__ __forceinline__ void flag_wait(const int* p, int tgt) {
  int sp = 0;
  while (flag_peek(p) < tgt) {
    __builtin_amdgcn_s_sleep(1);
    if (++sp > SPIN_CAP) break;        // bounded
  }
}

__device__ __forceinline__ u32x2 packbf4(fx4 v) {
  u32x2 r;
  r[0] = (uint32_t)f2bf(v[0]) | ((uint32_t)f2bf(v[1]) << 16);
  r[1] = (uint32_t)f2bf(v[2]) | ((uint32_t)f2bf(v[3]) << 16);
  return r;
}

// Fused free-running-poll + GEMM phase. 32x32 out-tile partials; wave w
// handles K-slice [256w,256w+256), fed by producers nj' = 8w..8w+7 (producer
// p covers A-load pairs A[2p],A[2p+1]). Lane p (p<8) repeatedly issues a
// dwordx4 flag-line load into f WITHOUT any waitcnt, and checks the register
// contents as-is: flag words are monotone counters, so old/new/torn reads
// can only false-negative. Newly-ready producers get their A loads issued
// immediately (fixed regs; MFMA accumulation order is free). NO waitcnt
// inside the loop (R15 lesson). MFMAs run as 4 independent chains (R17).
// Partials to red4[w][row*32+col]
// (C: col=lane&31, row=(reg&3)+8*(reg>>2)+4*(lane>>5)).
template <bool UNI>
__device__ __forceinline__ void gemm_phase_pipe(const short* __restrict__ abuf,
                                                const short* __restrict__ wl,
                                                float* __restrict__ red4, int tid,
                                                const int* __restrict__ flags, int tgt) {
  const int lane = tid & 63, w = tid >> 6;
  const int m = lane & 31, h = lane >> 5;
  const short* ap = abuf + (32 * w + h) * 256 + m * 8;
  const short* bp = wl + (32 * w + h) * 256 + m * 8;
  const int* fp = flags + lane * FSTR;       // meaningful for lane<8
  short8 A[16] = {};
  i32x4 f = {0, 0, 0, 0};                    // 0 < any tgt (tgt >= 1)
  unsigned issuedm = 0;
  int sp = 0;
  const bool poller = (lane < 8);

#define ISSUE_PAIR(p)                                                          \
  if (newly & (1u << (p))) {                                                   \
    if (UNI) {                                                                 \
      asm volatile("global_load_dwordx4 %0, %1, off sc0"                       \
                   : "=v"(A[2 * (p)]) : "v"(ap + (2 * (p)) * 512) : "memory"); \
      asm volatile("global_load_dwordx4 %0, %1, off sc0"                       \
                   : "=v"(A[2 * (p) + 1]) : "v"(ap + (2 * (p) + 1) * 512) : "memory"); \
    } else {                                                                   \
      asm volatile("global_load_dwordx4 %0, %1, off sc0 sc1"                   \
                   : "=v"(A[2 * (p)]) : "v"(ap + (2 * (p)) * 512) : "memory"); \
      asm volatile("global_load_dwordx4 %0, %1, off sc0 sc1"                   \
                   : "=v"(A[2 * (p) + 1]) : "v"(ap + (2 * (p) + 1) * 512) : "memory"); \
    }                                                                          \
  }

#pragma unroll 1
  while (issuedm != 0xFFu) {
    // issue a fresh flag sample into f; DO NOT wait for it. The check below
    // reads whatever the registers currently hold (monotone -> safe).
    if (poller)
      asm volatile("global_load_dwordx4 %0, %1, off sc0 sc1"
                   : "=v"(f) : "v"(fp) : "memory");
    bool mine = poller && (f[0] >= tgt) && (f[1] >= tgt) &&
                (f[2] >= tgt) && (f[3] >= tgt);
    unsigned ready = (unsigned)(__ballot(mine) & 0xFFull);
    unsigned newly = ready & ~issuedm;
    if (newly) {
      ISSUE_PAIR(0) ISSUE_PAIR(1) ISSUE_PAIR(2) ISSUE_PAIR(3)
      ISSUE_PAIR(4) ISSUE_PAIR(5) ISSUE_PAIR(6) ISSUE_PAIR(7)
      issuedm |= newly;
    }
    if (issuedm != 0xFFu) {
      __builtin_amdgcn_s_sleep(4);     // ~107ns pacing; bounds in-flight queue
      if (++sp > SPIN_CAP) break;      // bounded: garbage result, not a hang
    }
  }
#undef ISSUE_PAIR

  asm volatile("s_waitcnt vmcnt(0)"
               : "+v"(A[0]), "+v"(A[1]), "+v"(A[2]), "+v"(A[3]),
                 "+v"(A[4]), "+v"(A[5]), "+v"(A[6]), "+v"(A[7]),
                 "+v"(A[8]), "+v"(A[9]), "+v"(A[10]), "+v"(A[11]),
                 "+v"(A[12]), "+v"(A[13]), "+v"(A[14]), "+v"(A[15])
               :: "memory");
  // 4 independent accumulator chains: breaks the 16-deep dependent-MFMA
  // latency chain (K-partial reassociation is exact-add-order change only).
  fx16 ac0 = 0.0f, ac1 = 0.0f, ac2 = 0.0f, ac3 = 0.0f;
#pragma unroll
  for (int i = 0; i < 4; ++i) {
    ac0 = __builtin_amdgcn_mfma_f32_32x32x16_bf16(
        A[4 * i + 0], *(const short8*)(bp + (4 * i + 0) * 512), ac0, 0, 0, 0);
    ac1 = __builtin_amdgcn_mfma_f32_32x32x16_bf16(
        A[4 * i + 1], *(const short8*)(bp + (4 * i + 1) * 512), ac1, 0, 0, 0);
    ac2 = __builtin_amdgcn_mfma_f32_32x32x16_bf16(
        A[4 * i + 2], *(const short8*)(bp + (4 * i + 2) * 512), ac2, 0, 0, 0);
    ac3 = __builtin_amdgcn_mfma_f32_32x32x16_bf16(
        A[4 * i + 3], *(const short8*)(bp + (4 * i + 3) * 512), ac3, 0, 0, 0);
  }
  fx16 acc = (ac0 + ac1) + (ac2 + ac3);
#pragma unroll
  for (int i = 0; i < 16; ++i)
    red4[w * 1024 + ((i & 3) + 8 * (i >> 2) + 4 * h) * 32 + m] = acc[i];
}

extern "C" __global__ void __launch_bounds__(256)
hpcrnn_kernel(const int* __restrict__ cue,
              const float* __restrict__ ec3_last,
              const float* __restrict__ ec5_last,
              const float* __restrict__ ca1bias,
              const float* __restrict__ wca3ca1,
              const float* __restrict__ wec3ca1,
              const float* __restrict__ wca1ec5,
              const float* __restrict__ wca1act,
              const float* __restrict__ actbias,
              float* __restrict__ out,
              char* __restrict__ ws)
{
  extern __shared__ __attribute__((aligned(16))) char lds[];
  short* w1l  = (short*)(lds + LDS_W1);
  short* w2l  = (short*)(lds + LDS_W2);
  float* red4 = (float*)(lds + LDS_RED4);
  float* drvl = (float*)(lds + LDS_DRV);
  int*   unil = (int*)(lds + LDS_UNI);

  const int tid = threadIdx.x;
  const int bi  = blockIdx.x & 7;    // batch group; %8 == XCD residue heuristic
  const int nj  = blockIdx.x >> 3;   // N chunk (32 cols)
  const int R   = bi * 32, C = nj * 32;

  short* ec3buf = (short*)(ws + OFF_EC3);
  short* ca1buf = (short*)(ws + OFF_CA1);
  float* driveg = (float*)(ws + OFF_DRIVE);
  int*   ec3flag = (int*)(ws + OFF_EC3F);
  int*   ca1flag = (int*)(ws + OFF_CA1F);
  int*   drvflag = (int*)(ws + OFF_DRVF);
  int*   grpmask = (int*)(ws + OFF_GRP);         // lines: grpmask[bi*FSTR]
  int*   grpcnt  = (int*)(ws + OFF_GRP) + 512;   // lines: grpcnt[bi*FSTR]
  const int fbase = bi * 32;

  // ---- post group membership (XCD id), agent scope ----
  if (tid == 0) {
    int xcc;
    asm volatile("s_getreg_b32 %0, hwreg(HW_REG_XCC_ID)" : "=s"(xcc));
    __hip_atomic_fetch_or(&grpmask[bi * FSTR], 1 << (xcc & 31), __ATOMIC_RELAXED, __HIP_MEMORY_SCOPE_AGENT);
    __hip_atomic_fetch_add(&grpcnt[bi * FSTR], 1, __ATOMIC_RELAXED, __HIP_MEMORY_SCOPE_AGENT);
  }

  // ---- weights -> LDS, bf16, CHUNKED [g=(k>>3)][n=0..31][k&7] ----
  {
    const int c = tid & 31;
    for (int k = tid >> 5; k < FEAT; k += 8) {
      const int idx = ((k >> 3) * 32 + c) * 8 + (k & 7);
      w1l[idx] = (short)f2bf(wec3ca1[k * FEAT + C + c]);
      w2l[idx] = (short)f2bf(wca1ec5[k * FEAT + C + c]);
    }
  }

  // ---- resolve group XCD-uniformity (bounded; cap -> uni=false fallback) ----
  if (tid == 0) {
    flag_wait(&grpcnt[bi * FSTR], 32);
    int cnt = flag_peek(&grpcnt[bi * FSTR]);
    int mv  = __hip_atomic_load(&grpmask[bi * FSTR], __ATOMIC_RELAXED, __HIP_MEMORY_SCOPE_AGENT);
    unil[0] = (cnt >= 32 && __popc(mv) == 1) ? 1 : 0;
  }
  __syncthreads();
  const bool uni = (unil[0] != 0);

  // ---- per-thread element mapping: 1 row x 4 consecutive cols ----
  const int r  = tid >> 3;
  const int c0 = (tid & 7) * 4;
  const int rg = R + r;
  const int cg = C + c0;
  const size_t stoff = (size_t)(((cg >> 3) * 32 + r) * 8 + (c0 & 7));
  const size_t gbase = (size_t)bi * GSTRIDE;
  const int lane = tid & 63, wv = tid >> 6;

  const fx4 biasv  = *(const fx4*)(ca1bias + cg);
  const fx4 wact01 = *(const fx4*)(wca1act + cg * 2);
  const fx4 wact23 = *(const fx4*)(wca1act + cg * 2 + 4);
  fx4 ec3v = *(const fx4*)(ec3_last + (size_t)rg * FEAT + cg);
  fx4 ec5v = *(const fx4*)(ec5_last + (size_t)rg * FEAT + cg);
  fx4 ca1v = 0.0f;

  // ---- publish initial ec3 (per-wave: wave drains its rows, lane0 stores 1) ----
  ex_store(ec3buf + gbase + stoff, packbf4(ec3v), uni);
  VM_DRAIN();
  if (lane == 0) flag_store(&ec3flag[(fbase + nj) * FSTR + wv], 1);

  // ---- drive precompute: t === bi (mod 8), cols C..C+31 (always LLC path) ----
  {
    float* dred = red4;
    const int g = tid >> 5, n = tid & 31;
    for (int t = bi; t < NSTEP; t += 8) {
      float part = 0.0f;
      const float tf = (float)t;
      for (int c = g * 128; c < g * 128 + 128; ++c) {
        float d = (float)c * (100.0f / 1023.0f) - tf;
        part += __expf(d * d * -0.02f) * wca3ca1[c * FEAT + C + n];
      }
      __syncthreads();
      dred[g * 32 + n] = part;
      __syncthreads();
      if (g == 0) {
        float s = 0.0f;
#pragma unroll
        for (int gg = 0; gg < 8; ++gg) s += dred[gg * 32 + n];
        llc_store_f32(driveg + t * FEAT + C + n, s);
      }
    }
    VM_DRAIN();
    __syncthreads();
    if (tid == 0) {
      flag_add(&drvflag[nj * FSTR]);
      flag_wait(&drvflag[nj * FSTR], 8);
    }
    __syncthreads();
    for (int i = tid; i < NSTEP * 32; i += 256) {
      float v;
      asm volatile("global_load_dword %0, %1, off sc0 sc1"
                   : "=v"(v) : "v"(driveg + (i >> 5) * FEAT + C + (i & 31)) : "memory");
      asm volatile("s_waitcnt vmcnt(0)" : "+v"(v) :: "memory");
      drvl[i] = v;
    }
    __syncthreads();
  }

  // =================== main recurrence ===================
  for (int t = 0; t < NSTEP; ++t) {
    const size_t par = (size_t)(t & 1) * PSTRIDE;
    const int tgt = t + 1;             // value-encoded: ec3@t stored t+1 ahead

    // ---- phase 1: ca1 = relu(drive*(1+sig(ec3@w1)) - bias) ----
    // wave wv's K-slice depends only on producers nj' in [8wv, 8wv+8)
    if (uni) gemm_phase_pipe<true >(ec3buf + par + gbase, w1l, red4, tid,
                                    ec3flag + (fbase + 8 * wv) * FSTR, tgt);
    else     gemm_phase_pipe<false>(ec3buf + par + gbase, w1l, red4, tid,
                                    ec3flag + (fbase + 8 * wv) * FSTR, tgt);
    __syncthreads();                                  // partials ready

    {
      const int e0 = 4 * tid;
      fx4 p0 = *(const fx4*)(red4 + e0);
      fx4 p1 = *(const fx4*)(red4 + 1024 + e0);
      fx4 p2 = *(const fx4*)(red4 + 2048 + e0);
      fx4 p3 = *(const fx4*)(red4 + 3072 + e0);
      const fx4 dv = *(const fx4*)(drvl + t * 32 + c0);
#pragma unroll
      for (int j = 0; j < 4; ++j) {
        float dot = (p0[j] + p1[j]) + (p2[j] + p3[j]);
        float v = dv[j] * (1.0f + sigm(dot)) - biasv[j];
        ca1v[j] = fmaxf(v, 0.0f);
      }
      ex_store(ca1buf + par + gbase + stoff, packbf4(ca1v), uni);
    }
    VM_DRAIN();                                       // this wave's rows landed
    if (lane == 0) flag_store(&ca1flag[(fbase + nj) * FSTR + wv], t + 1);  // per-wave value
    if (rg == 0) *(fx4*)(out + O_CAH + t * FEAT + cg) = ca1v;   // off critical path
    __syncthreads();                                  // red4 reuse protection

    // ---- phase 2: ec5 += ca1@w2 ; squash ; ec3 = ec5*ec3 ; cue mask ----
    if (uni) gemm_phase_pipe<true >(ca1buf + par + gbase, w2l, red4, tid,
                                    ca1flag + (fbase + 8 * wv) * FSTR, tgt);
    else     gemm_phase_pipe<false>(ca1buf + par + gbase, w2l, red4, tid,
                                    ca1flag + (fbase + 8 * wv) * FSTR, tgt);
    __syncthreads();                                  // partials ready

    {
      const int e0 = 4 * tid;
      fx4 p0 = *(const fx4*)(red4 + e0);
      fx4 p1 = *(const fx4*)(red4 + 1024 + e0);
      fx4 p2 = *(const fx4*)(red4 + 2048 + e0);
      fx4 p3 = *(const fx4*)(red4 + 3072 + e0);
#pragma unroll
      for (int j = 0; j < 4; ++j) {
        float e5 = ec5v[j] + ((p0[j] + p1[j]) + (p2[j] + p3[j]));  // 10*TS = 1.0
        e5 = 0.69f + 0.3f * sigm(4.0f * (e5 - 0.3f));
        ec5v[j] = e5;
        ec3v[j] = e5 * ec3v[j];
      }
      if (t == 16 || t == 24) {
        const int s = (t == 24) ? 1 : 0;
        i32x4 m = *(const i32x4*)(cue + (size_t)rg * 2048 + s * 1024 + cg);
#pragma unroll
        for (int j = 0; j < 4; ++j)
          if (m[j]) ec3v[j] = 0.4f * ec3v[j] + 0.6f;
      }
      if (t < NSTEP - 1) {
        const size_t parn = (size_t)((t + 1) & 1) * PSTRIDE;
        ex_store(ec3buf + parn + gbase + stoff, packbf4(ec3v), uni);
      }
    }
    VM_DRAIN();
    if (lane == 0 && t < NSTEP - 1)
      flag_store(&ec3flag[(fbase + nj) * FSTR + wv], t + 2);     // per-wave value
    if (rg == 0) {                                    // off critical path
      *(fx4*)(out + O_E3H + t * FEAT + cg) = ec3v;
      *(fx4*)(out + O_E5H + t * FEAT + cg) = ec5v;
    }
    __syncthreads();                                  // red4 reuse protection
  }

  // ---- epilogue: finals + actCell ----
  float* ared = red4;
  if (tid < 64) ared[tid] = 0.0f;
  __syncthreads();
  {
    float p0 = ca1v[0] * wact01[0] + ca1v[1] * wact01[2] +
               ca1v[2] * wact23[0] + ca1v[3] * wact23[2];
    float p1 = ca1v[0] * wact01[1] + ca1v[1] * wact01[3] +
               ca1v[2] * wact23[1] + ca1v[3] * wact23[3];
    atomicAdd(&ared[r * 2 + 0], p0);
    atomicAdd(&ared[r * 2 + 1], p1);
  }
  *(fx4*)(out + O_E3 + (size_t)rg * FEAT + cg) = ec3v;
  *(fx4*)(out + O_E5 + (size_t)rg * FEAT + cg) = ec5v;
  *(fx4*)(out + O_CA + (size_t)rg * FEAT + cg) = ca1v;
  __syncthreads();
  if (tid < 64) {
    float v = ared[tid];
    if (nj == 0) v += actbias[tid & 1];
    atomicAdd(&out[O_ACT + (R + (tid >> 1)) * 2 + (tid & 1)], v);
  }
}

extern "C" void kernel_launch(void* const* d_in, const int* in_sizes, int n_in,
                              void* d_out, int out_size, void* d_ws, size_t ws_size,
                              hipStream_t stream) {
  (void)in_sizes; (void)n_in; (void)out_size;
  if (ws_size < WS_NEED) return;

  const int*   cue      = (const int*)  d_in[0];
  const float* ec3_last = (const float*)d_in[1];
  const float* ec5_last = (const float*)d_in[2];
  // d_in[3] = ca1_last: dead in the reference (overwritten before use)
  const float* ca1bias  = (const float*)d_in[4];
  const float* wca3ca1  = (const float*)d_in[5];
  const float* wec3ca1  = (const float*)d_in[6];
  const float* wca1ec5  = (const float*)d_in[7];
  const float* wca1act  = (const float*)d_in[8];
  const float* actbias  = (const float*)d_in[9];

  char* ws = (char*)d_ws;
  hipMemsetAsync(ws + OFF_EC3F, 0, WS_NEED - OFF_EC3F, stream);  // all flag lines -> 0
  hipMemsetAsync(d_out, 0, 512 * sizeof(float), stream);

  hipFuncSetAttribute(reinterpret_cast<const void*>(hpcrnn_kernel),
                      hipFuncAttributeMaxDynamicSharedMemorySize, LDS_TOTAL);

  hipLaunchKernelGGL(hpcrnn_kernel, dim3(256), dim3(256), LDS_TOTAL, stream,
                     cue, ec3_last, ec5_last, ca1bias, wca3ca1, wec3ca1,
                     wca1ec5, wca1act, actbias, (float*)d_out, ws);
}

// Round 6
// 622.607 us; speedup vs baseline: 1.1134x; 1.1134x over previous
//
#include <hip/hip_runtime.h>
#include <stdint.h>

// ---------------- problem constants ----------------
#define NSTEP 100
#define FEAT  1024
#define SPIN_CAP (1 << 16)   // bounded waits

typedef __attribute__((ext_vector_type(8)))  short short8;
typedef __attribute__((ext_vector_type(4)))  float fx4;
typedef __attribute__((ext_vector_type(16))) float fx16;
typedef __attribute__((ext_vector_type(2)))  unsigned int u32x2;
typedef __attribute__((ext_vector_type(4)))  int i32x4;

// ---------------- workspace layout (bytes) ----------------
// R18 = R16 (free-running poll, 607us best) + poll-loop micro-order.
// R17 post-mortem: 4-way MFMA chain split REGRESSED (637us) -- with 4
// waves/CU sharing the matrix pipe, dependent-chain stalls are already
// hidden by TLP; phase is MFMA-throughput-bound. Reverted.
// R18 attacks the two consumer-side residuals left in the R16 loop:
// (a) DRAIN EXCESS: vmcnt retires IN ISSUE ORDER, so the pre-MFMA vmcnt(0)
//     waits for the youngest in-flight poll (LLC RTT ~500-600cy) issued up
//     to the detection instant. Fix: check-first loop order -- the
//     detecting iteration issues NO new poll, so the youngest poll is >=1
//     iteration old at the drain and its RTT is mostly elapsed.
// (b) DETECTION QUANTUM: s_sleep(4)->s_sleep(2) (~53ns sampling). Poll
//     traffic x2 is within the headroom R10/R13 established.
// Hardware facts R4-R17: DATA plane is XCD-L2-local (sc0, R5); flag
// SIGNALING must be agent-scope at the LLC (~1-1.5us/hop) -- L2-scope flag
// polling falsified 3x (R4 atomics, R6 stores, R11 probe); poll-RATE-
// reduction falsified (R10); flag-per-128B-line: -45us (R13); store-flags
// (no RMW): -20us (R14); blocking-poll pipelining via vmcnt(N): falsified,
// conflates with fused A-loads (R15, +150us); free-running monotone poll
// (no waitcnt in loop): -34us (R16); MFMA chain-split: falsified, TLP
// already hides MFMA latency (R17, +30us); single-wave and per-wave-tile
// structures regressed (R8/R9): 4-SIMD split-K + 2 barriers is the local opt.
// Exchange: parity dbuf, 8 groups x (32 rows x 1024 cols) bf16; per-wave
// value-encoded flags (line = 4 wave-words; init=1, ca1@t=t+1, ec3@t=t+2).
// Element (group-local row m, col c) at short index ((c>>3)*32+m)*8+(c&7).
#define OFF_EC3   0u
#define OFF_CA1   (1u << 20)
#define OFF_DRIVE (2u << 20)
#define OFF_EC3F  (OFF_DRIVE + 425984u)   // drive needs 100*1024*4 = 409600
#define OFF_CA1F  (OFF_EC3F + 32768u)     // 256 lines * 128B (4 wave-words each)
#define OFF_DRVF  (OFF_CA1F + 32768u)     // 256 lines * 128B
#define OFF_GRP   (OFF_DRVF + 4096u)      // 32 lines * 128B
#define WS_NEED   (OFF_GRP + 4096u)       // grpmask lines @+0, grpcnt lines @+2048

#define FSTR 32                        // ints per flag line (128 B)

#define GSTRIDE 32768                  // shorts per group (32*1024)
#define PSTRIDE (8 * GSTRIDE)          // shorts per parity buffer

// ---------------- output layout (float elems) ----------------
#define O_ACT 0
#define O_E3H 512
#define O_E5H (512 + 102400)
#define O_CAH (512 + 204800)
#define O_E3  (512 + 307200)
#define O_E5  (O_E3 + 262144)
#define O_CA  (O_E5 + 262144)

// ---------------- LDS layout (bytes) ----------------
#define LDS_W1    0
#define LDS_W2    65536
#define LDS_RED4  131072               // 4*1024 f32 = 16384
#define LDS_DRV   147456               // 100*32 f32 = 12800
#define LDS_UNI   160256               // 1 int
#define LDS_TOTAL 160272               // <= 163840

__device__ __forceinline__ unsigned short f2bf(float x) {
  uint32_t u = __builtin_bit_cast(uint32_t, x);
  uint32_t r = (u + 0x7FFFu + ((u >> 16) & 1u)) >> 16;   // RNE
  return (unsigned short)r;
}
__device__ __forceinline__ float sigm(float x) { return 1.0f / (1.0f + __expf(-x)); }

#define VM_DRAIN() asm volatile("s_waitcnt vmcnt(0)" ::: "memory")

// data-plane store: uni -> dirty line in shared XCD L2; else -> LLC coherent
__device__ __forceinline__ void ex_store(void* p, u32x2 v, bool uni) {
  if (uni) asm volatile("global_store_dwordx2 %0, %1, off sc0"     :: "v"(p), "v"(v) : "memory");
  else     asm volatile("global_store_dwordx2 %0, %1, off sc0 sc1" :: "v"(p), "v"(v) : "memory");
}
__device__ __forceinline__ void llc_store_f32(float* p, float v) {
  asm volatile("global_store_dword %0, %1, off sc0 sc1" :: "v"(p), "v"(v) : "memory");
}
// control plane: agent scope at the LLC, always (the only HW-working protocol)
// Value-encoded flags: plain agent-scope store (no RMW), monotone values.
__device__ __forceinline__ void flag_store(int* p, int v) {
  __hip_atomic_store(p, v, __ATOMIC_RELAXED, __HIP_MEMORY_SCOPE_AGENT);
}
__device__ __forceinline__ void flag_add(int* p) {            // off-critical-path only
  __hip_atomic_fetch_add(p, 1, __ATOMIC_RELAXED, __HIP_MEMORY_SCOPE_AGENT);
}
__device__ __forceinline__ int flag_peek(const int* p) {
  return __hip_atomic_load(p, __ATOMIC_RELAXED, __HIP_MEMORY_SCOPE_AGENT);
}
__device__ __forceinline__ void flag_wait(const int* p, int tgt) {
  int sp = 0;
  while (flag_peek(p) < tgt) {
    __builtin_amdgcn_s_sleep(1);
    if (++sp > SPIN_CAP) break;        // bounded
  }
}

__device__ __forceinline__ u32x2 packbf4(fx4 v) {
  u32x2 r;
  r[0] = (uint32_t)f2bf(v[0]) | ((uint32_t)f2bf(v[1]) << 16);
  r[1] = (uint32_t)f2bf(v[2]) | ((uint32_t)f2bf(v[3]) << 16);
  return r;
}

// Fused free-running-poll + GEMM phase. 32x32 out-tile partials; wave w
// handles K-slice [256w,256w+256), fed by producers nj' = 8w..8w+7 (producer
// p covers A-load pairs A[2p],A[2p+1]). Lane p (p<8) keeps a dwordx4
// flag-line load streaming into f WITHOUT any waitcnt; the check reads the
// registers as-is (flag words are monotone counters: old/new/torn reads only
// false-negative, never false-positive). CHECK-FIRST order: the iteration
// that completes detection issues NO new poll, so the youngest outstanding
// poll at the pre-MFMA vmcnt(0) is >=1 iteration old (drain-excess fix, R18).
// NO waitcnt inside the loop (R15 lesson). Single MFMA chain (R17 lesson).
// Partials to red4[w][row*32+col]
// (C: col=lane&31, row=(reg&3)+8*(reg>>2)+4*(lane>>5)).
template <bool UNI>
__device__ __forceinline__ void gemm_phase_pipe(const short* __restrict__ abuf,
                                                const short* __restrict__ wl,
                                                float* __restrict__ red4, int tid,
                                                const int* __restrict__ flags, int tgt) {
  const int lane = tid & 63, w = tid >> 6;
  const int m = lane & 31, h = lane >> 5;
  const short* ap = abuf + (32 * w + h) * 256 + m * 8;
  const short* bp = wl + (32 * w + h) * 256 + m * 8;
  const int* fp = flags + lane * FSTR;       // meaningful for lane<8
  short8 A[16] = {};
  i32x4 f = {0, 0, 0, 0};                    // 0 < any tgt (tgt >= 1)
  unsigned issuedm = 0;
  int sp = 0;
  const bool poller = (lane < 8);

#define ISSUE_PAIR(p)                                                          \
  if (newly & (1u << (p))) {                                                   \
    if (UNI) {                                                                 \
      asm volatile("global_load_dwordx4 %0, %1, off sc0"                       \
                   : "=v"(A[2 * (p)]) : "v"(ap + (2 * (p)) * 512) : "memory"); \
      asm volatile("global_load_dwordx4 %0, %1, off sc0"                       \
                   : "=v"(A[2 * (p) + 1]) : "v"(ap + (2 * (p) + 1) * 512) : "memory"); \
    } else {                                                                   \
      asm volatile("global_load_dwordx4 %0, %1, off sc0 sc1"                   \
                   : "=v"(A[2 * (p)]) : "v"(ap + (2 * (p)) * 512) : "memory"); \
      asm volatile("global_load_dwordx4 %0, %1, off sc0 sc1"                   \
                   : "=v"(A[2 * (p) + 1]) : "v"(ap + (2 * (p) + 1) * 512) : "memory"); \
    }                                                                          \
  }

#pragma unroll 1
  while (true) {
    // 1) check current register contents (stale/torn-safe: monotone flags)
    bool mine = poller && (f[0] >= tgt) && (f[1] >= tgt) &&
                (f[2] >= tgt) && (f[3] >= tgt);
    unsigned ready = (unsigned)(__ballot(mine) & 0xFFull);
    unsigned newly = ready & ~issuedm;
    if (newly) {
      ISSUE_PAIR(0) ISSUE_PAIR(1) ISSUE_PAIR(2) ISSUE_PAIR(3)
      ISSUE_PAIR(4) ISSUE_PAIR(5) ISSUE_PAIR(6) ISSUE_PAIR(7)
      issuedm |= newly;
    }
    // 2) exit BEFORE issuing another poll: youngest outstanding poll stays
    //    >=1 iteration old -> pre-MFMA vmcnt(0) drain excess ~0.
    if (issuedm == 0xFFu) break;
    // 3) refresh sample (no wait), pace, bound.
    if (poller)
      asm volatile("global_load_dwordx4 %0, %1, off sc0 sc1"
                   : "=v"(f) : "v"(fp) : "memory");
    __builtin_amdgcn_s_sleep(2);       // ~53ns sampling quantum
    if (++sp > SPIN_CAP) break;        // bounded: garbage result, not a hang
  }
#undef ISSUE_PAIR

  asm volatile("s_waitcnt vmcnt(0)"
               : "+v"(A[0]), "+v"(A[1]), "+v"(A[2]), "+v"(A[3]),
                 "+v"(A[4]), "+v"(A[5]), "+v"(A[6]), "+v"(A[7]),
                 "+v"(A[8]), "+v"(A[9]), "+v"(A[10]), "+v"(A[11]),
                 "+v"(A[12]), "+v"(A[13]), "+v"(A[14]), "+v"(A[15])
               :: "memory");
  fx16 acc = 0.0f;
#pragma unroll
  for (int i = 0; i < 16; ++i) {
    short8 b = *(const short8*)(bp + i * 512);
    acc = __builtin_amdgcn_mfma_f32_32x32x16_bf16(A[i], b, acc, 0, 0, 0);
  }
#pragma unroll
  for (int i = 0; i < 16; ++i)
    red4[w * 1024 + ((i & 3) + 8 * (i >> 2) + 4 * h) * 32 + m] = acc[i];
}

extern "C" __global__ void __launch_bounds__(256)
hpcrnn_kernel(const int* __restrict__ cue,
              const float* __restrict__ ec3_last,
              const float* __restrict__ ec5_last,
              const float* __restrict__ ca1bias,
              const float* __restrict__ wca3ca1,
              const float* __restrict__ wec3ca1,
              const float* __restrict__ wca1ec5,
              const float* __restrict__ wca1act,
              const float* __restrict__ actbias,
              float* __restrict__ out,
              char* __restrict__ ws)
{
  extern __shared__ __attribute__((aligned(16))) char lds[];
  short* w1l  = (short*)(lds + LDS_W1);
  short* w2l  = (short*)(lds + LDS_W2);
  float* red4 = (float*)(lds + LDS_RED4);
  float* drvl = (float*)(lds + LDS_DRV);
  int*   unil = (int*)(lds + LDS_UNI);

  const int tid = threadIdx.x;
  const int bi  = blockIdx.x & 7;    // batch group; %8 == XCD residue heuristic
  const int nj  = blockIdx.x >> 3;   // N chunk (32 cols)
  const int R   = bi * 32, C = nj * 32;

  short* ec3buf = (short*)(ws + OFF_EC3);
  short* ca1buf = (short*)(ws + OFF_CA1);
  float* driveg = (float*)(ws + OFF_DRIVE);
  int*   ec3flag = (int*)(ws + OFF_EC3F);
  int*   ca1flag = (int*)(ws + OFF_CA1F);
  int*   drvflag = (int*)(ws + OFF_DRVF);
  int*   grpmask = (int*)(ws + OFF_GRP);         // lines: grpmask[bi*FSTR]
  int*   grpcnt  = (int*)(ws + OFF_GRP) + 512;   // lines: grpcnt[bi*FSTR]
  const int fbase = bi * 32;

  // ---- post group membership (XCD id), agent scope ----
  if (tid == 0) {
    int xcc;
    asm volatile("s_getreg_b32 %0, hwreg(HW_REG_XCC_ID)" : "=s"(xcc));
    __hip_atomic_fetch_or(&grpmask[bi * FSTR], 1 << (xcc & 31), __ATOMIC_RELAXED, __HIP_MEMORY_SCOPE_AGENT);
    __hip_atomic_fetch_add(&grpcnt[bi * FSTR], 1, __ATOMIC_RELAXED, __HIP_MEMORY_SCOPE_AGENT);
  }

  // ---- weights -> LDS, bf16, CHUNKED [g=(k>>3)][n=0..31][k&7] ----
  {
    const int c = tid & 31;
    for (int k = tid >> 5; k < FEAT; k += 8) {
      const int idx = ((k >> 3) * 32 + c) * 8 + (k & 7);
      w1l[idx] = (short)f2bf(wec3ca1[k * FEAT + C + c]);
      w2l[idx] = (short)f2bf(wca1ec5[k * FEAT + C + c]);
    }
  }

  // ---- resolve group XCD-uniformity (bounded; cap -> uni=false fallback) ----
  if (tid == 0) {
    flag_wait(&grpcnt[bi * FSTR], 32);
    int cnt = flag_peek(&grpcnt[bi * FSTR]);
    int mv  = __hip_atomic_load(&grpmask[bi * FSTR], __ATOMIC_RELAXED, __HIP_MEMORY_SCOPE_AGENT);
    unil[0] = (cnt >= 32 && __popc(mv) == 1) ? 1 : 0;
  }
  __syncthreads();
  const bool uni = (unil[0] != 0);

  // ---- per-thread element mapping: 1 row x 4 consecutive cols ----
  const int r  = tid >> 3;
  const int c0 = (tid & 7) * 4;
  const int rg = R + r;
  const int cg = C + c0;
  const size_t stoff = (size_t)(((cg >> 3) * 32 + r) * 8 + (c0 & 7));
  const size_t gbase = (size_t)bi * GSTRIDE;
  const int lane = tid & 63, wv = tid >> 6;

  const fx4 biasv  = *(const fx4*)(ca1bias + cg);
  const fx4 wact01 = *(const fx4*)(wca1act + cg * 2);
  const fx4 wact23 = *(const fx4*)(wca1act + cg * 2 + 4);
  fx4 ec3v = *(const fx4*)(ec3_last + (size_t)rg * FEAT + cg);
  fx4 ec5v = *(const fx4*)(ec5_last + (size_t)rg * FEAT + cg);
  fx4 ca1v = 0.0f;

  // ---- publish initial ec3 (per-wave: wave drains its rows, lane0 stores 1) ----
  ex_store(ec3buf + gbase + stoff, packbf4(ec3v), uni);
  VM_DRAIN();
  if (lane == 0) flag_store(&ec3flag[(fbase + nj) * FSTR + wv], 1);

  // ---- drive precompute: t === bi (mod 8), cols C..C+31 (always LLC path) ----
  {
    float* dred = red4;
    const int g = tid >> 5, n = tid & 31;
    for (int t = bi; t < NSTEP; t += 8) {
      float part = 0.0f;
      const float tf = (float)t;
      for (int c = g * 128; c < g * 128 + 128; ++c) {
        float d = (float)c * (100.0f / 1023.0f) - tf;
        part += __expf(d * d * -0.02f) * wca3ca1[c * FEAT + C + n];
      }
      __syncthreads();
      dred[g * 32 + n] = part;
      __syncthreads();
      if (g == 0) {
        float s = 0.0f;
#pragma unroll
        for (int gg = 0; gg < 8; ++gg) s += dred[gg * 32 + n];
        llc_store_f32(driveg + t * FEAT + C + n, s);
      }
    }
    VM_DRAIN();
    __syncthreads();
    if (tid == 0) {
      flag_add(&drvflag[nj * FSTR]);
      flag_wait(&drvflag[nj * FSTR], 8);
    }
    __syncthreads();
    for (int i = tid; i < NSTEP * 32; i += 256) {
      float v;
      asm volatile("global_load_dword %0, %1, off sc0 sc1"
                   : "=v"(v) : "v"(driveg + (i >> 5) * FEAT + (i & 31) + C) : "memory");
      asm volatile("s_waitcnt vmcnt(0)" : "+v"(v) :: "memory");
      drvl[i] = v;
    }
    __syncthreads();
  }

  // =================== main recurrence ===================
  for (int t = 0; t < NSTEP; ++t) {
    const size_t par = (size_t)(t & 1) * PSTRIDE;
    const int tgt = t + 1;             // value-encoded: ec3@t stored t+1 ahead

    // ---- phase 1: ca1 = relu(drive*(1+sig(ec3@w1)) - bias) ----
    // wave wv's K-slice depends only on producers nj' in [8wv, 8wv+8)
    if (uni) gemm_phase_pipe<true >(ec3buf + par + gbase, w1l, red4, tid,
                                    ec3flag + (fbase + 8 * wv) * FSTR, tgt);
    else     gemm_phase_pipe<false>(ec3buf + par + gbase, w1l, red4, tid,
                                    ec3flag + (fbase + 8 * wv) * FSTR, tgt);
    __syncthreads();                                  // partials ready

    {
      const int e0 = 4 * tid;
      fx4 p0 = *(const fx4*)(red4 + e0);
      fx4 p1 = *(const fx4*)(red4 + 1024 + e0);
      fx4 p2 = *(const fx4*)(red4 + 2048 + e0);
      fx4 p3 = *(const fx4*)(red4 + 3072 + e0);
      const fx4 dv = *(const fx4*)(drvl + t * 32 + c0);
#pragma unroll
      for (int j = 0; j < 4; ++j) {
        float dot = (p0[j] + p1[j]) + (p2[j] + p3[j]);
        float v = dv[j] * (1.0f + sigm(dot)) - biasv[j];
        ca1v[j] = fmaxf(v, 0.0f);
      }
      ex_store(ca1buf + par + gbase + stoff, packbf4(ca1v), uni);
    }
    VM_DRAIN();                                       // this wave's rows landed
    if (lane == 0) flag_store(&ca1flag[(fbase + nj) * FSTR + wv], t + 1);  // per-wave value
    if (rg == 0) *(fx4*)(out + O_CAH + t * FEAT + cg) = ca1v;   // off critical path
    __syncthreads();                                  // red4 reuse protection

    // ---- phase 2: ec5 += ca1@w2 ; squash ; ec3 = ec5*ec3 ; cue mask ----
    if (uni) gemm_phase_pipe<true >(ca1buf + par + gbase, w2l, red4, tid,
                                    ca1flag + (fbase + 8 * wv) * FSTR, tgt);
    else     gemm_phase_pipe<false>(ca1buf + par + gbase, w2l, red4, tid,
                                    ca1flag + (fbase + 8 * wv) * FSTR, tgt);
    __syncthreads();                                  // partials ready

    {
      const int e0 = 4 * tid;
      fx4 p0 = *(const fx4*)(red4 + e0);
      fx4 p1 = *(const fx4*)(red4 + 1024 + e0);
      fx4 p2 = *(const fx4*)(red4 + 2048 + e0);
      fx4 p3 = *(const fx4*)(red4 + 3072 + e0);
#pragma unroll
      for (int j = 0; j < 4; ++j) {
        float e5 = ec5v[j] + ((p0[j] + p1[j]) + (p2[j] + p3[j]));  // 10*TS = 1.0
        e5 = 0.69f + 0.3f * sigm(4.0f * (e5 - 0.3f));
        ec5v[j] = e5;
        ec3v[j] = e5 * ec3v[j];
      }
      if (t == 16 || t == 24) {
        const int s = (t == 24) ? 1 : 0;
        i32x4 m = *(const i32x4*)(cue + (size_t)rg * 2048 + s * 1024 + cg);
#pragma unroll
        for (int j = 0; j < 4; ++j)
          if (m[j]) ec3v[j] = 0.4f * ec3v[j] + 0.6f;
      }
      if (t < NSTEP - 1) {
        const size_t parn = (size_t)((t + 1) & 1) * PSTRIDE;
        ex_store(ec3buf + parn + gbase + stoff, packbf4(ec3v), uni);
      }
    }
    VM_DRAIN();
    if (lane == 0 && t < NSTEP - 1)
      flag_store(&ec3flag[(fbase + nj) * FSTR + wv], t + 2);     // per-wave value
    if (rg == 0) {                                    // off critical path
      *(fx4*)(out + O_E3H + t * FEAT + cg) = ec3v;
      *(fx4*)(out + O_E5H + t * FEAT + cg) = ec5v;
    }
    __syncthreads();                                  // red4 reuse protection
  }

  // ---- epilogue: finals + actCell ----
  float* ared = red4;
  if (tid < 64) ared[tid] = 0.0f;
  __syncthreads();
  {
    float p0 = ca1v[0] * wact01[0] + ca1v[1] * wact01[2] +
               ca1v[2] * wact23[0] + ca1v[3] * wact23[2];
    float p1 = ca1v[0] * wact01[1] + ca1v[1] * wact01[3] +
               ca1v[2] * wact23[1] + ca1v[3] * wact23[3];
    atomicAdd(&ared[r * 2 + 0], p0);
    atomicAdd(&ared[r * 2 + 1], p1);
  }
  *(fx4*)(out + O_E3 + (size_t)rg * FEAT + cg) = ec3v;
  *(fx4*)(out + O_E5 + (size_t)rg * FEAT + cg) = ec5v;
  *(fx4*)(out + O_CA + (size_t)rg * FEAT + cg) = ca1v;
  __syncthreads();
  if (tid < 64) {
    float v = ared[tid];
    if (nj == 0) v += actbias[tid & 1];
    atomicAdd(&out[O_ACT + (R + (tid >> 1)) * 2 + (tid & 1)], v);
  }
}

extern "C" void kernel_launch(void* const* d_in, const int* in_sizes, int n_in,
                              void* d_out, int out_size, void* d_ws, size_t ws_size,
                              hipStream_t stream) {
  (void)in_sizes; (void)n_in; (void)out_size;
  if (ws_size < WS_NEED) return;

  const int*   cue      = (const int*)  d_in[0];
  const float* ec3_last = (const float*)d_in[1];
  const float* ec5_last = (const float*)d_in[2];
  // d_in[3] = ca1_last: dead in the reference (overwritten before use)
  const float* ca1bias  = (const float*)d_in[4];
  const float* wca3ca1  = (const float*)d_in[5];
  const float* wec3ca1  = (const float*)d_in[6];
  const float* wca1ec5  = (const float*)d_in[7];
  const float* wca1act  = (const float*)d_in[8];
  const float* actbias  = (const float*)d_in[9];

  char* ws = (char*)d_ws;
  hipMemsetAsync(ws + OFF_EC3F, 0, WS_NEED - OFF_EC3F, stream);  // all flag lines -> 0
  hipMemsetAsync(d_out, 0, 512 * sizeof(float), stream);

  hipFuncSetAttribute(reinterpret_cast<const void*>(hpcrnn_kernel),
                      hipFuncAttributeMaxDynamicSharedMemorySize, LDS_TOTAL);

  hipLaunchKernelGGL(hpcrnn_kernel, dim3(256), dim3(256), LDS_TOTAL, stream,
                     cue, ec3_last, ec5_last, ca1bias, wca3ca1, wec3ca1,
                     wca1ec5, wca1act, actbias, (float*)d_out, ws);
}